// Round 3
// baseline (1036.259 us; speedup 1.0000x reference)
//
#include <hip/hip_runtime.h>

// CCN layer promotion, split into two ordered dispatches:
//   promotions[n,c,a,b,s] = feat[neigh[n,c],s] iff neigh[n,a]==neigh[n,c]==neigh[n,b], else 0
//   new_parts == neigh (pre-sorted by setup), written as float.
//
// ~97% of promotions is structurally zero (nonzero needs a,b in the duplicate
// group of c; groups are almost always singletons for random neighbors).
// Kernel 1: pure zero-stream over the 983 MB promotions region — no loads, no
//           LDS, no branches. Doubles as a pure-store roofline measurement
//           (visible as its own dispatch in rocprof).
// Kernel 2: writes new_parts + the sparse nonzero entries (duplicate-aware),
//           ordered after kernel 1 by stream semantics.

constexpr int NN = 20000;
constexpr int DD = 16;
constexpr int FF = 3;
constexpr int PROMO_PER_NODE = DD * DD * DD * FF;                 // 12288 floats
constexpr long long PROMO_TOTAL = (long long)NN * PROMO_PER_NODE; // 245,760,000
constexpr long long PROMO_V4 = PROMO_TOTAL / 4;                   // 61,440,000 float4s

typedef float v4f __attribute__((ext_vector_type(4)));

// ---------------- Kernel 1: pure store stream ----------------
constexpr int ZBLOCKS  = 2048;   // cap per G11; grid-stride the rest
constexpr int ZTHREADS = 256;

__global__ __launch_bounds__(ZTHREADS) void zero_promotions(float* __restrict__ out)
{
    const v4f z = {0.0f, 0.0f, 0.0f, 0.0f};
    v4f* o = reinterpret_cast<v4f*>(out);
    const long long stride = (long long)ZBLOCKS * ZTHREADS;
    for (long long i = (long long)blockIdx.x * ZTHREADS + threadIdx.x;
         i < PROMO_V4; i += stride)
        __builtin_nontemporal_store(z, o + i);   // 64 lanes x 16B = 1KB/instr, coalesced
}

// ---------------- Kernel 2: sparse nonzeros + new_parts ----------------
// One block per node, 256 threads = one (c,a) pair each.
__global__ __launch_bounds__(256) void scatter_nonzeros(
    const float* __restrict__ tensors,
    const int* __restrict__ neigh,
    float* __restrict__ out)
{
    const int n = blockIdx.x;
    const int t = threadIdx.x;

    __shared__ int nv[DD];
    if (t < DD) {
        const int id = neigh[n * DD + t];
        nv[t] = id;
        // output 1: new_parts (== sorted neigh) as float
        out[(size_t)PROMO_TOTAL + (size_t)n * DD + t] = (float)id;
    }
    __syncthreads();

    const int c   = t >> 4;    // 0..15
    const int a   = t & 15;    // 0..15
    const int nvc = nv[c];

    if (nv[a] == nvc) {        // chi[n,c,a] == 1
        // 240 KB tensors table: L2-resident gather
        const float f0 = tensors[(size_t)nvc * FF + 0];
        const float f1 = tensors[(size_t)nvc * FF + 1];
        const float f2 = tensors[(size_t)nvc * FF + 2];
        float* base = out + (size_t)n * PROMO_PER_NODE + (size_t)((c * DD + a) * DD) * FF;
#pragma unroll
        for (int b = 0; b < DD; ++b) {
            if (nv[b] == nvc) { // chi[n,c,b] == 1
                base[b * FF + 0] = f0;
                base[b * FF + 1] = f1;
                base[b * FF + 2] = f2;
            }
        }
    }
}

extern "C" void kernel_launch(void* const* d_in, const int* in_sizes, int n_in,
                              void* d_out, int out_size, void* d_ws, size_t ws_size,
                              hipStream_t stream) {
    const float* tensors = (const float*)d_in[0];  // [N, F] float32
    const int*   neigh   = (const int*)d_in[1];    // [N, D] int32 (sorted rows)
    float*       out     = (float*)d_out;          // promotions flat + new_parts flat

    zero_promotions<<<ZBLOCKS, ZTHREADS, 0, stream>>>(out);
    scatter_nonzeros<<<NN, 256, 0, stream>>>(tensors, neigh, out);
}

// Round 4
// 961.625 us; speedup vs baseline: 1.0776x; 1.0776x over previous
//
#include <hip/hip_runtime.h>

// CCN layer promotion, split into two ordered dispatches:
//   promotions[n,c,a,b,s] = feat[neigh[n,c],s] iff neigh[n,a]==neigh[n,c]==neigh[n,b], else 0
//   new_parts == neigh (pre-sorted by setup), written as float.
//
// R4 = discriminator experiment. The harness poison-fill reports 3.94 GB written
// at 6.2 TB/s with ~10% occupancy and PLAIN stores; every structure we've tried
// (NT/plain, high/low occupancy, fused/split) caps at 2.8-3.05 TB/s. Either the
// WRITE_SIZE formula is 4x-inflated (=> 3.05 TB/s is the chip's store ceiling and
// R2 was already at the composed roofline), or plain low-occupancy grid-stride
// stores really do 6+ TB/s. This zero pass mimics the fill exactly:
// plain dwordx4, 208 blocks x 256 threads (~10% occupancy), grid-stride.

constexpr int NN = 20000;
constexpr int DD = 16;
constexpr int FF = 3;
constexpr int PROMO_PER_NODE = DD * DD * DD * FF;                 // 12288 floats
constexpr long long PROMO_TOTAL = (long long)NN * PROMO_PER_NODE; // 245,760,000
constexpr long long PROMO_V4 = PROMO_TOTAL / 4;                   // 61,440,000 float4s

typedef float v4f __attribute__((ext_vector_type(4)));

// ---------------- Kernel 1: fill-mimic zero stream ----------------
constexpr int ZBLOCKS  = 208;    // ~832 waves = ~10% occupancy, mimicking rocclr fill
constexpr int ZTHREADS = 256;

__global__ __launch_bounds__(ZTHREADS) void zero_promotions_mimic(float* __restrict__ out)
{
    const v4f z = {0.0f, 0.0f, 0.0f, 0.0f};
    v4f* o = reinterpret_cast<v4f*>(out);
    const long long stride = (long long)ZBLOCKS * ZTHREADS;   // 53248 float4s = 832 KB
    for (long long i = (long long)blockIdx.x * ZTHREADS + threadIdx.x;
         i < PROMO_V4; i += stride)
        o[i] = z;    // PLAIN store (L2 write-combining path), 64 lanes x 16B coalesced
}

// ---------------- Kernel 2: sparse nonzeros + new_parts (verified R3) ----------------
// One block per node, 256 threads = one (c,a) pair each.
__global__ __launch_bounds__(256) void scatter_nonzeros(
    const float* __restrict__ tensors,
    const int* __restrict__ neigh,
    float* __restrict__ out)
{
    const int n = blockIdx.x;
    const int t = threadIdx.x;

    __shared__ int nv[DD];
    if (t < DD) {
        const int id = neigh[n * DD + t];
        nv[t] = id;
        // output 1: new_parts (== sorted neigh) as float
        out[(size_t)PROMO_TOTAL + (size_t)n * DD + t] = (float)id;
    }
    __syncthreads();

    const int c   = t >> 4;    // 0..15
    const int a   = t & 15;    // 0..15
    const int nvc = nv[c];

    if (nv[a] == nvc) {        // chi[n,c,a] == 1
        // 240 KB tensors table: L2-resident gather
        const float f0 = tensors[(size_t)nvc * FF + 0];
        const float f1 = tensors[(size_t)nvc * FF + 1];
        const float f2 = tensors[(size_t)nvc * FF + 2];
        float* base = out + (size_t)n * PROMO_PER_NODE + (size_t)((c * DD + a) * DD) * FF;
#pragma unroll
        for (int b = 0; b < DD; ++b) {
            if (nv[b] == nvc) { // chi[n,c,b] == 1
                base[b * FF + 0] = f0;
                base[b * FF + 1] = f1;
                base[b * FF + 2] = f2;
            }
        }
    }
}

extern "C" void kernel_launch(void* const* d_in, const int* in_sizes, int n_in,
                              void* d_out, int out_size, void* d_ws, size_t ws_size,
                              hipStream_t stream) {
    const float* tensors = (const float*)d_in[0];  // [N, F] float32
    const int*   neigh   = (const int*)d_in[1];    // [N, D] int32 (sorted rows)
    float*       out     = (float*)d_out;          // promotions flat + new_parts flat

    zero_promotions_mimic<<<ZBLOCKS, ZTHREADS, 0, stream>>>(out);
    scatter_nonzeros<<<NN, 256, 0, stream>>>(tensors, neigh, out);
}